// Round 4
// baseline (3313.658 us; speedup 1.0000x reference)
//
#include <hip/hip_runtime.h>
#include <cmath>

#define T_STEPS 127
#define BATCHN  4096
#define DIN     64
#define SEQ     128

// ---- workspace layout ----
// shorts region (fp16x2 MFMA B-fragments; piece1 stored pre-scaled by 2048):
//   GB = gate weights: idx = (((kt*64 + ct)*2 + p)*64 + lane)*8 + j
//        element: piece_p( W[n=ct*16+(lane&15)][k=kt*32+(lane>>4)*8+j] ), W=[W_ih|W_hh] cols
//   HB = head weights (mu|var|velo|switch stacked as 256 out cols):
//        idx = (((kt*16 + ct)*2 + p)*64 + lane)*8 + j, same element formula, k in [0,256)
#define GBSH   655360
#define HBSH   131072
#define TOTSH  (GBSH + HBSH)
// float region (float index into ws):
#define F0     (TOTSH / 2)       // 393216
#define BG_F   F0                // gate biases b_ih+b_hh [1024]
#define BH_F   (F0 + 1024)       // head biases [256]
#define WNP_F  (F0 + 1280)       // W_next packed fp32 [16][64][4]
#define F_END  (F0 + 5376)

// ---- output float offsets (concat of 5 outputs) ----
#define O_STATES 0L
#define O_GENS   33292288L
#define O_ONOFF  33812480L
#define O_TNG    34332672L
#define O_TG     34856960L

#define P1SCALE   2048.0f
#define P1INV     4.8828125e-4f   // 1/2048

typedef float    float4v __attribute__((ext_vector_type(4)));
typedef _Float16 f16x8   __attribute__((ext_vector_type(8)));

__device__ __forceinline__ float sigmoid_f(float x) {
    return 1.0f / (1.0f + __expf(-x));
}
__device__ __forceinline__ float tanh_f(float x) {
    float cx = fminf(15.0f, fmaxf(-15.0f, x));
    float e = __expf(2.0f * cx);
    return (e - 1.0f) / (e + 1.0f);
}
// 3-way interleaved butterfly reduction: hides ds_bpermute latency 3-wide
__device__ __forceinline__ void wave_sum64_3(float& a, float& b, float& c) {
    #pragma unroll
    for (int off = 32; off > 0; off >>= 1) {
        a += __shfl_xor(a, off, 64);
        b += __shfl_xor(b, off, 64);
        c += __shfl_xor(c, off, 64);
    }
}
// fp16x2 split: p0 = fp16(v), p1s = fp16((v - p0) * 2048)  (pre-scaled to avoid subnormals)
__device__ __forceinline__ void f16x2_split(float v, _Float16& p0, _Float16& p1s) {
    p0 = (_Float16)v;
    float r = v - (float)p0;
    p1s = (_Float16)(r * P1SCALE);
}

__global__ void prep_kernel(const float* __restrict__ W_ih, const float* __restrict__ W_hh,
                            const float* __restrict__ b_ih, const float* __restrict__ b_hh,
                            const float* __restrict__ W_mu, const float* __restrict__ W_var,
                            const float* __restrict__ W_velo, const float* __restrict__ W_switch,
                            const float* __restrict__ b_mu, const float* __restrict__ b_var,
                            const float* __restrict__ b_velo, const float* __restrict__ b_switch,
                            const float* __restrict__ W_next, float* __restrict__ ws) {
    int idx = blockIdx.x * blockDim.x + threadIdx.x;
    int stride = gridDim.x * blockDim.x;

    _Float16* gh = (_Float16*)ws;

    // fp16x2 gate-weight fragments
    for (int s = idx; s < GBSH; s += stride) {
        int j = s & 7, l = (s >> 3) & 63, r = s >> 9;
        int p = r & 1, tile = r >> 1, ct = tile & 63, kt = tile >> 6;
        int n = ct * 16 + (l & 15);
        int k = kt * 32 + ((l >> 4) << 3) + j;
        float v = (k < 64) ? W_ih[n * 64 + k] : W_hh[n * 256 + (k - 64)];
        _Float16 p0, p1s;
        f16x2_split(v, p0, p1s);
        gh[s] = (p == 0) ? p0 : p1s;
    }

    // fp16x2 head-weight fragments
    for (int s = idx; s < HBSH; s += stride) {
        int j = s & 7, l = (s >> 3) & 63, r = s >> 9;
        int p = r & 1, tile = r >> 1, ct = tile & 15, kt = tile >> 4;
        int n = ct * 16 + (l & 15);
        int k = kt * 32 + ((l >> 4) << 3) + j;
        int hsel = n >> 6, jf = n & 63;
        const float* W = (hsel == 0) ? W_mu : (hsel == 1) ? W_var : (hsel == 2) ? W_velo : W_switch;
        float v = W[jf * 256 + k];
        _Float16 p0, p1s;
        f16x2_split(v, p0, p1s);
        gh[GBSH + s] = (p == 0) ? p0 : p1s;
    }

    // fp32 region
    for (int i = F0 + idx; i < F_END; i += stride) {
        float v;
        if (i < BH_F) {                      // gate biases
            int n = i - BG_F;
            v = b_ih[n] + b_hh[n];
        } else if (i < WNP_F) {              // head biases
            int c = i - BH_F;
            int hsel = c >> 6, jf = c & 63;
            const float* b = (hsel == 0) ? b_mu : (hsel == 1) ? b_var : (hsel == 2) ? b_velo : b_switch;
            v = b[jf];
        } else {                             // W_next packed [kc][feat][kk]
            int t = i - WNP_F;
            int kk = t & 3, jf = (t >> 2) & 63, kc = t >> 8;
            int k = kc * 4 + kk;
            v = W_next[jf * 64 + k];
        }
        ws[i] = v;
    }
}

// 1024 threads = 16 waves = 4 waves/SIMD; grid 256 = 1 block/CU.
__global__ __launch_bounds__(1024, 4)
void model_kernel(const float* __restrict__ data, const float* __restrict__ locs,
                  const float* __restrict__ W_loc, const float* __restrict__ b_loc,
                  const float* __restrict__ b_next, const float* __restrict__ W_gen,
                  const float* __restrict__ b_gen, const float* __restrict__ W_on,
                  const float* __restrict__ b_on, const float* __restrict__ eps,
                  const float* __restrict__ ws, float* __restrict__ out) {
    // mu(->z in place), logvar, velo, switch; stride 68 floats
    __shared__ __align__(16) float headbuf[4][16][68];
    // fp16x2 planes of [x | h] (cols 0..63 = x, 64..319 = h), pre-split MFMA A-fragments.
    // plane1 is pre-scaled by 2048. stride 328 halfs = 656 B (16B-aligned rows)
    __shared__ __align__(16) _Float16 af0[16][328];
    __shared__ __align__(16) _Float16 af1[16][328];
    // W_next staged in LDS [16][64][4] floats
    __shared__ __align__(16) float wnl[4096];
    // total LDS: 17408 + 2*10496 + 16384 = 54784 B

    const int tid  = threadIdx.x;
    const int r0   = blockIdx.x * 16;
    const int w    = tid >> 6;      // wave 0..15
    const int ln   = tid & 63;      // lane
    const int ln15 = ln & 15;
    const int quad = ln >> 4;

    // ---- init: x = data[:,0,:] (regs + f16 planes), h0 = locs @ W_loc.T + b_loc ----
    float x_reg;
    {
        float v = data[(size_t)(r0 + w) * SEQ * DIN + ln];
        x_reg = v;
        _Float16 p0, p1s; f16x2_split(v, p0, p1s);
        af0[w][ln] = p0; af1[w][ln] = p1s;
    }
    {
        int j = tid & 255, rh = tid >> 8;   // rh 0..3, 4 rows each
        float w0 = W_loc[j * 2], w1 = W_loc[j * 2 + 1], bl = b_loc[j];
        #pragma unroll
        for (int rr = 0; rr < 4; ++rr) {
            int r = rh * 4 + rr;
            float hv = locs[(r0 + r) * 2] * w0 + locs[(r0 + r) * 2 + 1] * w1 + bl;
            _Float16 p0, p1s; f16x2_split(hv, p0, p1s);
            af0[r][64 + j] = p0; af1[r][64 + j] = p1s;
        }
    }
    for (int i = tid; i < 4096; i += 1024) wnl[i] = ws[WNP_F + i];
    if (tid < 16) {
        out[O_TNG + (long)(r0 + tid) * 128] = 0.0f;
        out[O_TG  + (long)(r0 + tid) * 128] = 0.0f;
    }
    __syncthreads();

    // persistent per-lane LSTM cell state, C-fragment layout:
    // c_st[rg] = c[row = quad*4+rg][col = w*16 + ln15]
    float c_st[4] = {0.0f, 0.0f, 0.0f, 0.0f};

    float bgc[4];
    #pragma unroll
    for (int g = 0; g < 4; ++g)
        bgc[g] = ws[BG_F + g * 256 + w * 16 + ln15];

    const float bhv  = ws[BH_F + w * 16 + ln15];
    const float bgen = b_gen[0];
    const float bon  = b_on[0];
    const float bnv  = b_next[ln];
    const float wgv  = W_gen[ln];
    const float wov  = W_on[ln];

    const f16x8* __restrict__ gb = (const f16x8*)ws;
    const f16x8* __restrict__ hb = gb + (GBSH / 8);

    // persistent gate accumulators: bias + h-part(t) carried into iteration t,
    // x-part added at iteration top. accg2 holds the pre-scaled correction sum.
    float4v accg1[4], accg2[4];
    #pragma unroll
    for (int g = 0; g < 4; ++g) {
        float b = bgc[g];
        accg1[g][0] = b; accg1[g][1] = b; accg1[g][2] = b; accg1[g][3] = b;
        accg2[g][0] = 0.0f; accg2[g][1] = 0.0f; accg2[g][2] = 0.0f; accg2[g][3] = 0.0f;
    }
    // prologue: h-part of gates(0) from h0 fragments
    #pragma unroll 2
    for (int kt = 0; kt < 8; ++kt) {
        int ke = 64 + kt * 32 + quad * 8;
        f16x8 A0 = *(const f16x8*)&af0[ln15][ke];
        f16x8 A1 = *(const f16x8*)&af1[ln15][ke];
        int kbase = (kt + 2) * 8192 + ln;
        #pragma unroll
        for (int g = 0; g < 4; ++g) {
            int idx = kbase + (g * 16 + w) * 128;
            f16x8 B0 = gb[idx];
            f16x8 B1 = gb[idx + 64];
            accg1[g] = __builtin_amdgcn_mfma_f32_16x16x32_f16(A0, B0, accg1[g], 0, 0, 0);
            accg2[g] = __builtin_amdgcn_mfma_f32_16x16x32_f16(A0, B1, accg2[g], 0, 0, 0);
            accg2[g] = __builtin_amdgcn_mfma_f32_16x16x32_f16(A1, B0, accg2[g], 0, 0, 0);
        }
    }

    for (int t = 0; t < T_STEPS; ++t) {
        // prefetch eps for this step (used in Phase C) — hides HBM latency under fused loop
        const float ep = eps[((size_t)t * BATCHN + r0 + w) * 64 + ln];

        // ---------- x-part of gates(t): k = 0..63 (x columns, fresh from prev Phase D) ----------
        #pragma unroll
        for (int ktx = 0; ktx < 2; ++ktx) {
            int ke = ktx * 32 + quad * 8;
            f16x8 A0 = *(const f16x8*)&af0[ln15][ke];
            f16x8 A1 = *(const f16x8*)&af1[ln15][ke];
            int kbase = ktx * 8192 + ln;
            #pragma unroll
            for (int g = 0; g < 4; ++g) {
                int idx = kbase + (g * 16 + w) * 128;
                f16x8 B0 = gb[idx];
                f16x8 B1 = gb[idx + 64];
                accg1[g] = __builtin_amdgcn_mfma_f32_16x16x32_f16(A0, B0, accg1[g], 0, 0, 0);
                accg2[g] = __builtin_amdgcn_mfma_f32_16x16x32_f16(A0, B1, accg2[g], 0, 0, 0);
                accg2[g] = __builtin_amdgcn_mfma_f32_16x16x32_f16(A1, B0, accg2[g], 0, 0, 0);
            }
        }

        // ---------- LSTM cell elementwise in C-layout; c stays in registers ----------
        float hval[4];
        #pragma unroll
        for (int rg = 0; rg < 4; ++rg) {
            float gi = fmaf(accg2[0][rg], P1INV, accg1[0][rg]);
            float gf = fmaf(accg2[1][rg], P1INV, accg1[1][rg]);
            float gg = fmaf(accg2[2][rg], P1INV, accg1[2][rg]);
            float go = fmaf(accg2[3][rg], P1INV, accg1[3][rg]);
            float iv = sigmoid_f(gi);
            float fv = sigmoid_f(gf);
            float gv = tanh_f(gg);
            float ov = sigmoid_f(go);
            float cn = fv * c_st[rg] + iv * gv;
            c_st[rg] = cn;
            hval[rg] = ov * tanh_f(cn);
        }
        // h-write needs no preceding barrier: since the end-of-step barrier, waves only
        // read x columns (0..63) and registers; h columns (64..319) are untouched.
        {
            int hcol = 64 + w * 16 + ln15;
            #pragma unroll
            for (int rg = 0; rg < 4; ++rg) {
                int row = quad * 4 + rg;
                _Float16 p0, p1s; f16x2_split(hval[rg], p0, p1s);
                af0[row][hcol] = p0;
                af1[row][hcol] = p1s;
            }
        }
        __syncthreads();   // B1: h(t) fragments visible to all waves

        // ---------- FUSED loop over h(t): heads(t) AND h-part of gates(t+1) ----------
        float4v hacc1, hacc2;
        hacc1[0] = bhv; hacc1[1] = bhv; hacc1[2] = bhv; hacc1[3] = bhv;
        hacc2[0] = 0.0f; hacc2[1] = 0.0f; hacc2[2] = 0.0f; hacc2[3] = 0.0f;
        #pragma unroll
        for (int g = 0; g < 4; ++g) {
            float b = bgc[g];
            accg1[g][0] = b; accg1[g][1] = b; accg1[g][2] = b; accg1[g][3] = b;
            accg2[g][0] = 0.0f; accg2[g][1] = 0.0f; accg2[g][2] = 0.0f; accg2[g][3] = 0.0f;
        }
        #pragma unroll 1
        for (int kt = 0; kt < 8; ++kt) {
            int ke = 64 + kt * 32 + quad * 8;
            f16x8 A0 = *(const f16x8*)&af0[ln15][ke];
            f16x8 A1 = *(const f16x8*)&af1[ln15][ke];
            // heads(t)
            int hidx = kt * 2048 + w * 128 + ln;
            f16x8 HB0 = hb[hidx];
            f16x8 HB1 = hb[hidx + 64];
            hacc1 = __builtin_amdgcn_mfma_f32_16x16x32_f16(A0, HB0, hacc1, 0, 0, 0);
            hacc2 = __builtin_amdgcn_mfma_f32_16x16x32_f16(A0, HB1, hacc2, 0, 0, 0);
            hacc2 = __builtin_amdgcn_mfma_f32_16x16x32_f16(A1, HB0, hacc2, 0, 0, 0);
            // h-part of gates(t+1)
            int kbase = (kt + 2) * 8192 + ln;
            #pragma unroll
            for (int g = 0; g < 4; ++g) {
                int idx = kbase + (g * 16 + w) * 128;
                f16x8 B0 = gb[idx];
                f16x8 B1 = gb[idx + 64];
                accg1[g] = __builtin_amdgcn_mfma_f32_16x16x32_f16(A0, B0, accg1[g], 0, 0, 0);
                accg2[g] = __builtin_amdgcn_mfma_f32_16x16x32_f16(A0, B1, accg2[g], 0, 0, 0);
                accg2[g] = __builtin_amdgcn_mfma_f32_16x16x32_f16(A1, B0, accg2[g], 0, 0, 0);
            }
        }
        {
            int n = w * 16 + ln15, hsel = n >> 6, f2 = n & 63;
            #pragma unroll
            for (int rg = 0; rg < 4; ++rg)
                headbuf[hsel][quad * 4 + rg][f2] = fmaf(hacc2[rg], P1INV, hacc1[rg]);
        }
        __syncthreads();   // B2: headbuf complete

        // ---------- Phase C: z = eps * exp(0.5*logvar) + mu, in place (row w only: same-wave) ----------
        headbuf[0][w][ln] = ep * __expf(0.5f * headbuf[1][w][ln]) + headbuf[0][w][ln];
        // no barrier: row w of headbuf[0] is only read below by wave w itself

        // ---------- Phase D: delta, state update, scalars, totals, outputs ----------
        {
            float dacc = bnv;
            #pragma unroll 4
            for (int kc = 0; kc < 16; ++kc) {
                float4 cw = *(const float4*)&wnl[(kc * 64 + ln) * 4];
                float4 zv = *(const float4*)&headbuf[0][w][kc * 4];
                dacc = fmaf(zv.x, cw.x, fmaf(zv.y, cw.y, fmaf(zv.z, cw.z, fmaf(zv.w, cw.w, dacc))));
            }
            float sv = (ln == 0) ? 0.0f : fmaxf(x_reg + dacc, 0.0f);
            float sa = sv;
            float sb = headbuf[2][w][ln] * wgv;
            float sc = headbuf[3][w][ln] * wov;
            wave_sum64_3(sa, sb, sc);
            float gen = fmaxf(sb + bgen, 0.0f);
            float onf = (sc + bon > 0.0f) ? 1.0f : 0.0f;
            float add = gen * onf;
            if (ln == 0) sv = add;
            float tpost = sa + add;
            out[O_STATES + (long)(r0 + w) * (127L * 64) + (long)t * 64 + ln] = sv;
            x_reg = sv;   // x_{t+1} stays in registers (static tid->element map)
            _Float16 p0, p1s; f16x2_split(sv, p0, p1s);
            af0[w][ln] = p0; af1[w][ln] = p1s;
            if (ln == 0) {
                long rb127 = (long)(r0 + w) * 127 + t;
                out[O_GENS  + rb127] = gen;
                out[O_ONOFF + rb127] = onf;
                long rb128 = (long)(r0 + w) * 128 + t + 1;
                out[O_TNG + rb128] = sa;
                out[O_TG  + rb128] = tpost;
            }
        }
        __syncthreads();   // B3: x(t+1) fragments visible; h(t) reads all done
    }
}

extern "C" void kernel_launch(void* const* d_in, const int* in_sizes, int n_in,
                              void* d_out, int out_size, void* d_ws, size_t ws_size,
                              hipStream_t stream) {
    const float* data     = (const float*)d_in[0];
    const float* locs     = (const float*)d_in[1];
    const float* W_ih     = (const float*)d_in[2];
    const float* W_hh     = (const float*)d_in[3];
    const float* b_ih     = (const float*)d_in[4];
    const float* b_hh     = (const float*)d_in[5];
    const float* W_mu     = (const float*)d_in[6];
    const float* b_mu     = (const float*)d_in[7];
    const float* W_var    = (const float*)d_in[8];
    const float* b_var    = (const float*)d_in[9];
    const float* W_velo   = (const float*)d_in[10];
    const float* b_velo   = (const float*)d_in[11];
    const float* W_switch = (const float*)d_in[12];
    const float* b_switch = (const float*)d_in[13];
    const float* W_gen    = (const float*)d_in[14];
    const float* b_gen    = (const float*)d_in[15];
    const float* W_on     = (const float*)d_in[16];
    const float* b_on     = (const float*)d_in[17];
    const float* W_next   = (const float*)d_in[18];
    const float* b_next   = (const float*)d_in[19];
    const float* W_loc    = (const float*)d_in[20];
    const float* b_loc    = (const float*)d_in[21];
    const float* eps      = (const float*)d_in[22];

    float* ws  = (float*)d_ws;
    float* out = (float*)d_out;

    prep_kernel<<<256, 256, 0, stream>>>(W_ih, W_hh, b_ih, b_hh,
                                         W_mu, W_var, W_velo, W_switch,
                                         b_mu, b_var, b_velo, b_switch,
                                         W_next, ws);
    model_kernel<<<256, 1024, 0, stream>>>(data, locs, W_loc, b_loc, b_next,
                                           W_gen, b_gen, W_on, b_on, eps, ws, out);
}

// Round 5
// 1817.411 us; speedup vs baseline: 1.8233x; 1.8233x over previous
//
#include <hip/hip_runtime.h>
#include <cmath>

#define T_STEPS 127
#define BATCHN  4096
#define DIN     64
#define SEQ     128

// ---- workspace layout ----
// shorts region (fp16 MFMA B-fragments):
//   GB = gate weights, MAIN PLANE ONLY (p0 fp16, 2 B/weight):
//        idx = ((kt*64 + ct)*64 + lane)*8 + j
//        element: fp16( W[n=ct*16+(lane&15)][k=kt*32+(lane>>4)*8+j] ), W=[W_ih|W_hh] cols
//   HB = head weights (mu|var|velo|switch stacked as 256 out cols), fp16x2
//        (piece1 pre-scaled by 2048): idx = (((kt*16 + ct)*2 + p)*64 + lane)*8 + j
#define GBSH   327680
#define HBSH   131072
#define TOTSH  (GBSH + HBSH)
// float region (float index into ws):
#define F0     (TOTSH / 2)       // 229376
#define BG_F   F0                // gate biases b_ih+b_hh [1024]
#define BH_F   (F0 + 1024)       // head biases [256]
#define WNP_F  (F0 + 1280)       // W_next packed fp32 [16][64][4]
#define F_END  (F0 + 5376)

// ---- output float offsets (concat of 5 outputs) ----
#define O_STATES 0L
#define O_GENS   33292288L
#define O_ONOFF  33812480L
#define O_TNG    34332672L
#define O_TG     34856960L

#define P1SCALE   2048.0f
#define P1INV     4.8828125e-4f   // 1/2048

typedef float    float4v __attribute__((ext_vector_type(4)));
typedef _Float16 f16x8   __attribute__((ext_vector_type(8)));

__device__ __forceinline__ float sigmoid_f(float x) {
    return 1.0f / (1.0f + __expf(-x));
}
__device__ __forceinline__ float tanh_f(float x) {
    float cx = fminf(15.0f, fmaxf(-15.0f, x));
    float e = __expf(2.0f * cx);
    return (e - 1.0f) / (e + 1.0f);
}
// 3-way interleaved butterfly reduction: hides ds_bpermute latency 3-wide
__device__ __forceinline__ void wave_sum64_3(float& a, float& b, float& c) {
    #pragma unroll
    for (int off = 32; off > 0; off >>= 1) {
        a += __shfl_xor(a, off, 64);
        b += __shfl_xor(b, off, 64);
        c += __shfl_xor(c, off, 64);
    }
}
// fp16x2 split: p0 = fp16(v), p1s = fp16((v - p0) * 2048)  (pre-scaled to avoid subnormals)
__device__ __forceinline__ void f16x2_split(float v, _Float16& p0, _Float16& p1s) {
    p0 = (_Float16)v;
    float r = v - (float)p0;
    p1s = (_Float16)(r * P1SCALE);
}

__global__ void prep_kernel(const float* __restrict__ W_ih, const float* __restrict__ W_hh,
                            const float* __restrict__ b_ih, const float* __restrict__ b_hh,
                            const float* __restrict__ W_mu, const float* __restrict__ W_var,
                            const float* __restrict__ W_velo, const float* __restrict__ W_switch,
                            const float* __restrict__ b_mu, const float* __restrict__ b_var,
                            const float* __restrict__ b_velo, const float* __restrict__ b_switch,
                            const float* __restrict__ W_next, float* __restrict__ ws) {
    int idx = blockIdx.x * blockDim.x + threadIdx.x;
    int stride = gridDim.x * blockDim.x;

    _Float16* gh = (_Float16*)ws;

    // fp16 gate-weight fragments (main plane only)
    for (int s = idx; s < GBSH; s += stride) {
        int j = s & 7, l = (s >> 3) & 63, tile = s >> 9;
        int ct = tile & 63, kt = tile >> 6;
        int n = ct * 16 + (l & 15);
        int k = kt * 32 + ((l >> 4) << 3) + j;
        float v = (k < 64) ? W_ih[n * 64 + k] : W_hh[n * 256 + (k - 64)];
        gh[s] = (_Float16)v;
    }

    // fp16x2 head-weight fragments
    for (int s = idx; s < HBSH; s += stride) {
        int j = s & 7, l = (s >> 3) & 63, r = s >> 9;
        int p = r & 1, tile = r >> 1, ct = tile & 15, kt = tile >> 4;
        int n = ct * 16 + (l & 15);
        int k = kt * 32 + ((l >> 4) << 3) + j;
        int hsel = n >> 6, jf = n & 63;
        const float* W = (hsel == 0) ? W_mu : (hsel == 1) ? W_var : (hsel == 2) ? W_velo : W_switch;
        float v = W[jf * 256 + k];
        _Float16 p0, p1s;
        f16x2_split(v, p0, p1s);
        gh[GBSH + s] = (p == 0) ? p0 : p1s;
    }

    // fp32 region
    for (int i = F0 + idx; i < F_END; i += stride) {
        float v;
        if (i < BH_F) {                      // gate biases
            int n = i - BG_F;
            v = b_ih[n] + b_hh[n];
        } else if (i < WNP_F) {              // head biases
            int c = i - BH_F;
            int hsel = c >> 6, jf = c & 63;
            const float* b = (hsel == 0) ? b_mu : (hsel == 1) ? b_var : (hsel == 2) ? b_velo : b_switch;
            v = b[jf];
        } else {                             // W_next packed [kc][feat][kk]
            int t = i - WNP_F;
            int kk = t & 3, jf = (t >> 2) & 63, kc = t >> 8;
            int k = kc * 4 + kk;
            v = W_next[jf * 64 + k];
        }
        ws[i] = v;
    }
}

// 1024 threads = 16 waves = 4 waves/SIMD; grid 256 = 1 block/CU.
__global__ __launch_bounds__(1024, 4)
void model_kernel(const float* __restrict__ data, const float* __restrict__ locs,
                  const float* __restrict__ W_loc, const float* __restrict__ b_loc,
                  const float* __restrict__ b_next, const float* __restrict__ W_gen,
                  const float* __restrict__ b_gen, const float* __restrict__ W_on,
                  const float* __restrict__ b_on, const float* __restrict__ eps,
                  const float* __restrict__ ws, float* __restrict__ out) {
    // mu(->z in place), logvar, velo, switch; stride 68 floats
    __shared__ __align__(16) float headbuf[4][16][68];
    // fp16x2 planes of [x | h] (cols 0..63 = x, 64..319 = h), pre-split MFMA A-fragments.
    // plane1 is pre-scaled by 2048. stride 328 halfs = 656 B (16B-aligned rows)
    __shared__ __align__(16) _Float16 af0[16][328];
    __shared__ __align__(16) _Float16 af1[16][328];
    // W_next staged in LDS [16][64][4] floats
    __shared__ __align__(16) float wnl[4096];
    // total LDS: 17408 + 2*10496 + 16384 = 54784 B

    const int tid  = threadIdx.x;
    const int r0   = blockIdx.x * 16;
    const int w    = tid >> 6;      // wave 0..15
    const int ln   = tid & 63;      // lane
    const int ln15 = ln & 15;
    const int quad = ln >> 4;

    // ---- init: x = data[:,0,:] (regs + f16 planes), h0 = locs @ W_loc.T + b_loc ----
    float x_reg;
    {
        float v = data[(size_t)(r0 + w) * SEQ * DIN + ln];
        x_reg = v;
        _Float16 p0, p1s; f16x2_split(v, p0, p1s);
        af0[w][ln] = p0; af1[w][ln] = p1s;
    }
    {
        int j = tid & 255, rh = tid >> 8;   // rh 0..3, 4 rows each
        float w0 = W_loc[j * 2], w1 = W_loc[j * 2 + 1], bl = b_loc[j];
        #pragma unroll
        for (int rr = 0; rr < 4; ++rr) {
            int r = rh * 4 + rr;
            float hv = locs[(r0 + r) * 2] * w0 + locs[(r0 + r) * 2 + 1] * w1 + bl;
            _Float16 p0, p1s; f16x2_split(hv, p0, p1s);
            af0[r][64 + j] = p0; af1[r][64 + j] = p1s;
        }
    }
    for (int i = tid; i < 4096; i += 1024) wnl[i] = ws[WNP_F + i];
    if (tid < 16) {
        out[O_TNG + (long)(r0 + tid) * 128] = 0.0f;
        out[O_TG  + (long)(r0 + tid) * 128] = 0.0f;
    }
    __syncthreads();

    // persistent per-lane LSTM cell state, C-fragment layout:
    // c_st[rg] = c[row = quad*4+rg][col = w*16 + ln15]
    float c_st[4] = {0.0f, 0.0f, 0.0f, 0.0f};

    float bgc[4];
    #pragma unroll
    for (int g = 0; g < 4; ++g)
        bgc[g] = ws[BG_F + g * 256 + w * 16 + ln15];

    const float bhv  = ws[BH_F + w * 16 + ln15];
    const float bgen = b_gen[0];
    const float bon  = b_on[0];
    const float bnv  = b_next[ln];
    const float wgv  = W_gen[ln];
    const float wov  = W_on[ln];

    const f16x8* __restrict__ gb = (const f16x8*)ws;
    const f16x8* __restrict__ hb = gb + (GBSH / 8);

    for (int t = 0; t < T_STEPS; ++t) {
        // prefetch eps for this step (used in Phase C) — hides HBM latency under Phase A/B
        const float ep = eps[((size_t)t * BATCHN + r0 + w) * 64 + ln];

        // ---------- Phase A: gates = [x|h] @ Wg^T + bg (B main plane fp16, A fp16x2) ----------
        // acc1 += A0*B0 ; acc2 += A1s*B0  (A1s pre-scaled by 2048) ; gates = acc1 + acc2/2048
        float4v acc1[4], acc2[4];
        #pragma unroll
        for (int g = 0; g < 4; ++g) {
            float b = bgc[g];
            acc1[g][0] = b; acc1[g][1] = b; acc1[g][2] = b; acc1[g][3] = b;
            acc2[g][0] = 0.0f; acc2[g][1] = 0.0f; acc2[g][2] = 0.0f; acc2[g][3] = 0.0f;
        }

        #pragma unroll 2
        for (int kt = 0; kt < 10; ++kt) {
            int ke = kt * 32 + quad * 8;
            f16x8 A0 = *(const f16x8*)&af0[ln15][ke];
            f16x8 A1 = *(const f16x8*)&af1[ln15][ke];
            int kbase = kt * 4096 + ln;
            #pragma unroll
            for (int g = 0; g < 4; ++g) {
                f16x8 B0 = gb[kbase + (g * 16 + w) * 64];
                acc1[g] = __builtin_amdgcn_mfma_f32_16x16x32_f16(A0, B0, acc1[g], 0, 0, 0);
                acc2[g] = __builtin_amdgcn_mfma_f32_16x16x32_f16(A1, B0, acc2[g], 0, 0, 0);
            }
        }

        // ---------- LSTM cell elementwise in C-layout; c stays in registers ----------
        float hval[4];
        #pragma unroll
        for (int rg = 0; rg < 4; ++rg) {
            float gi = fmaf(acc2[0][rg], P1INV, acc1[0][rg]);
            float gf = fmaf(acc2[1][rg], P1INV, acc1[1][rg]);
            float gg = fmaf(acc2[2][rg], P1INV, acc1[2][rg]);
            float go = fmaf(acc2[3][rg], P1INV, acc1[3][rg]);
            float iv = sigmoid_f(gi);
            float fv = sigmoid_f(gf);
            float gv = tanh_f(gg);
            float ov = sigmoid_f(go);
            float cn = fv * c_st[rg] + iv * gv;
            c_st[rg] = cn;
            hval[rg] = ov * tanh_f(cn);
        }
        __syncthreads();   // all waves finished reading af planes for gates
        {
            int hcol = 64 + w * 16 + ln15;
            #pragma unroll
            for (int rg = 0; rg < 4; ++rg) {
                int row = quad * 4 + rg;
                _Float16 p0, p1s; f16x2_split(hval[rg], p0, p1s);
                af0[row][hcol] = p0;
                af1[row][hcol] = p1s;
            }
        }
        __syncthreads();

        // ---------- Phase B: 4 heads = h @ W_head.T + b (fp16x2 MFMA, 1 tile/wave) ----------
        {
            float4v hacc1, hacc2;
            hacc1[0] = bhv; hacc1[1] = bhv; hacc1[2] = bhv; hacc1[3] = bhv;
            hacc2[0] = 0.0f; hacc2[1] = 0.0f; hacc2[2] = 0.0f; hacc2[3] = 0.0f;
            #pragma unroll 2
            for (int kt = 0; kt < 8; ++kt) {
                int ke = 64 + kt * 32 + quad * 8;
                f16x8 A0 = *(const f16x8*)&af0[ln15][ke];
                f16x8 A1 = *(const f16x8*)&af1[ln15][ke];
                int idx = kt * 2048 + w * 128 + ln;
                f16x8 B0 = hb[idx];
                f16x8 B1 = hb[idx + 64];
                hacc1 = __builtin_amdgcn_mfma_f32_16x16x32_f16(A0, B0, hacc1, 0, 0, 0);
                hacc2 = __builtin_amdgcn_mfma_f32_16x16x32_f16(A0, B1, hacc2, 0, 0, 0);
                hacc2 = __builtin_amdgcn_mfma_f32_16x16x32_f16(A1, B0, hacc2, 0, 0, 0);
            }
            int n = w * 16 + ln15, hsel = n >> 6, f2 = n & 63;
            #pragma unroll
            for (int rg = 0; rg < 4; ++rg)
                headbuf[hsel][quad * 4 + rg][f2] = fmaf(hacc2[rg], P1INV, hacc1[rg]);
        }
        __syncthreads();

        // ---------- Phase C: z = eps * exp(0.5*logvar) + mu, in place (row w only: same-wave) ----------
        headbuf[0][w][ln] = ep * __expf(0.5f * headbuf[1][w][ln]) + headbuf[0][w][ln];
        // no barrier: row w of headbuf[0] is only read below by wave w itself

        // ---------- Phase D: delta, state update, scalars, totals, outputs ----------
        {
            float dacc = bnv;
            #pragma unroll 4
            for (int kc = 0; kc < 16; ++kc) {
                float4 cw = *(const float4*)&wnl[(kc * 64 + ln) * 4];
                float4 zv = *(const float4*)&headbuf[0][w][kc * 4];
                dacc = fmaf(zv.x, cw.x, fmaf(zv.y, cw.y, fmaf(zv.z, cw.z, fmaf(zv.w, cw.w, dacc))));
            }
            float sv = (ln == 0) ? 0.0f : fmaxf(x_reg + dacc, 0.0f);
            float sa = sv;
            float sb = headbuf[2][w][ln] * wgv;
            float sc = headbuf[3][w][ln] * wov;
            wave_sum64_3(sa, sb, sc);
            float gen = fmaxf(sb + bgen, 0.0f);
            float onf = (sc + bon > 0.0f) ? 1.0f : 0.0f;
            float add = gen * onf;
            if (ln == 0) sv = add;
            float tpost = sa + add;
            out[O_STATES + (long)(r0 + w) * (127L * 64) + (long)t * 64 + ln] = sv;
            x_reg = sv;   // x_{t+1} stays in registers (static tid->element map)
            _Float16 p0, p1s; f16x2_split(sv, p0, p1s);
            af0[w][ln] = p0; af1[w][ln] = p1s;
            if (ln == 0) {
                long rb127 = (long)(r0 + w) * 127 + t;
                out[O_GENS  + rb127] = gen;
                out[O_ONOFF + rb127] = onf;
                long rb128 = (long)(r0 + w) * 128 + t + 1;
                out[O_TNG + rb128] = sa;
                out[O_TG  + rb128] = tpost;
            }
        }
        __syncthreads();
    }
}

extern "C" void kernel_launch(void* const* d_in, const int* in_sizes, int n_in,
                              void* d_out, int out_size, void* d_ws, size_t ws_size,
                              hipStream_t stream) {
    const float* data     = (const float*)d_in[0];
    const float* locs     = (const float*)d_in[1];
    const float* W_ih     = (const float*)d_in[2];
    const float* W_hh     = (const float*)d_in[3];
    const float* b_ih     = (const float*)d_in[4];
    const float* b_hh     = (const float*)d_in[5];
    const float* W_mu     = (const float*)d_in[6];
    const float* b_mu     = (const float*)d_in[7];
    const float* W_var    = (const float*)d_in[8];
    const float* b_var    = (const float*)d_in[9];
    const float* W_velo   = (const float*)d_in[10];
    const float* b_velo   = (const float*)d_in[11];
    const float* W_switch = (const float*)d_in[12];
    const float* b_switch = (const float*)d_in[13];
    const float* W_gen    = (const float*)d_in[14];
    const float* b_gen    = (const float*)d_in[15];
    const float* W_on     = (const float*)d_in[16];
    const float* b_on     = (const float*)d_in[17];
    const float* W_next   = (const float*)d_in[18];
    const float* b_next   = (const float*)d_in[19];
    const float* W_loc    = (const float*)d_in[20];
    const float* b_loc    = (const float*)d_in[21];
    const float* eps      = (const float*)d_in[22];

    float* ws  = (float*)d_ws;
    float* out = (float*)d_out;

    prep_kernel<<<256, 256, 0, stream>>>(W_ih, W_hh, b_ih, b_hh,
                                         W_mu, W_var, W_velo, W_switch,
                                         b_mu, b_var, b_velo, b_switch,
                                         W_next, ws);
    model_kernel<<<256, 1024, 0, stream>>>(data, locs, W_loc, b_loc, b_next,
                                           W_gen, b_gen, W_on, b_on, eps, ws, out);
}